// Round 15
// baseline (217.976 us; speedup 1.0000x reference)
//
#include <hip/hip_runtime.h>
#include <hip/hip_bf16.h>

#define NN 50000
#define NE 640000
#define HID 128

// ---- workspace layout (bytes) ----  (high-water 72,228,480 — R6-proven)
// agg   f32 [NN*128]   @ 0            25,600,000   \ zeroed by init_kernel
// hist  int [50000]    @ 25,600,000      200,000   /
// W1e   bf16[128*32]   @ 25,800,000        8,192
// W2p   bf16[128*128]  @ 25,808,192       32,768
// U1p   bf16[128*288]  @ 25,840,960       73,728
// U2p   bf16[128*128]  @ 25,914,688       32,768
// pos   int [50000]    @ 25,947,456      200,000
// csum  int [256]      @ 26,147,456        1,024
// sd    int2[NE]       @ 26,148,480    5,120,000   (dst-sorted {src,dst} pairs)
// efs   bf16[NE*32]    @ 31,268,480   40,960,000   (dst-sorted, bf16)
// Wpre  bf16[256*128]  = ALIASES efs head (dead before scatter; R8-proven)
// Ppre bf16[NN*256] lives in d_out (dead until node_kernel).

typedef __attribute__((ext_vector_type(8))) short bf8;  // 8 bf16 = 16B
typedef __attribute__((ext_vector_type(4))) float f4;
typedef __attribute__((ext_vector_type(2))) int i2;

#define MFMA(a, b, c) __builtin_amdgcn_mfma_f32_16x16x32_bf16(a, b, c, 0, 0, 0)

// Raw barrier: LDS visibility only (lgkmcnt), does NOT drain vmcnt.
#define SYNC() do { asm volatile("s_waitcnt lgkmcnt(0)" ::: "memory"); \
                    __builtin_amdgcn_s_barrier(); } while (0)

// f32 -> bf16 (RNE) via the official HW convert path. NO hand-written
// v_cvt_pk asm — convicted of NaN corruption in R7/R10.
__device__ __forceinline__ short f2bf(float f) {
    __hip_bfloat16 h = __float2bfloat16(f);
    union { __hip_bfloat16 h; short s; } v; v.h = h;
    return v.s;
}
__device__ __forceinline__ float bf2f(short s) {
    union { unsigned u; float f; } v; v.u = ((unsigned)(unsigned short)s) << 16;
    return v.f;
}
__device__ __forceinline__ float silu(float x) {
    return x * __builtin_amdgcn_rcpf(1.f + __expf(-x));
}

// ---------- init: pack weights (blocks 0..63) + zero agg/hist (blocks 64..255) ----------
__global__ __launch_bounds__(256)
void init_kernel(const float* __restrict__ mW1, const float* __restrict__ mW2,
                 const float* __restrict__ uW1, const float* __restrict__ uW2,
                 short* __restrict__ Wpre, short* __restrict__ W1e,
                 short* __restrict__ W2p, short* __restrict__ U1p,
                 short* __restrict__ U2p, f4* __restrict__ zero_base) {
    const int b = blockIdx.x, tid = threadIdx.x;
    if (b < 64) {
        const int stride = 64 * 256;
        const int idx = b * 256 + tid;
        // Wpre[cc][k]: cc<128 -> mW1[k][cc]; cc>=128 -> mW1[128+k][cc-128]
        for (int t = idx; t < 256 * 128; t += stride) {
            int cc = t / 128, k = t % 128;
            float v = (cc < 128) ? mW1[k * 128 + cc] : mW1[(128 + k) * 128 + (cc - 128)];
            Wpre[t] = f2bf(v);
        }
        for (int t = idx; t < 128 * 32; t += stride) {
            int c = t / 32, k = t % 32;
            W1e[t] = f2bf(mW1[(256 + k) * 128 + c]);
        }
        for (int t = idx; t < 128 * 128; t += stride)
            W2p[t] = f2bf(mW2[(t % 128) * 128 + (t / 128)]);
        for (int t = idx; t < 128 * 288; t += stride) {
            int n = t / 288, k = t % 288;
            U1p[t] = (k < 257) ? f2bf(uW1[k * 128 + n]) : (short)0;
        }
        for (int t = idx; t < 128 * 128; t += stride)
            U2p[t] = f2bf(uW2[(t % 128) * 128 + (t / 128)]);
    } else {
        // zero agg + hist: 25,800,000 B = 1,612,500 f4 exactly
        const int stride = 192 * 256;
        f4 z = {};
        for (int t = (b - 64) * 256 + tid; t < 1612500; t += stride)
            zero_base[t] = z;
    }
}

// ---------- prep: node_pre (blocks 0..781, packed-Wpre B-frags) | hist (782..999) ----------
__global__ __launch_bounds__(256, 3)
void prep_kernel(const float* __restrict__ nf, const float* __restrict__ coord,
                 const short* __restrict__ Wpre,
                 const float* __restrict__ mW1, const float* __restrict__ mb1,
                 const int* __restrict__ ei,
                 short* __restrict__ Ppre, int* __restrict__ hist) {
    const int b = blockIdx.x, tid = threadIdx.x;
    if (b < 782) {
        // Ppre[n] = [nf@W1src + c*w288 | nf@W1dst + c*w289 + mb1]  (R8-proven body)
        __shared__ short SH[64 * 264];   // A [64][136] then P [64][264] (phase-disjoint)
        __shared__ float scoord[64];
        short* A = SH;
        short* P = SH;
        const int nbase = b * 64;

        {   // stage nf -> bf16 A
            const int r = tid >> 2, q = tid & 3;
            const int node = nbase + r;
            short* Ar = A + r * 136 + q * 32;
            if (node < NN) {
                const float* p = nf + (long)node * HID + q * 32;
#pragma unroll
                for (int j = 0; j < 4; ++j) {
                    f4 v0 = *(const f4*)(p + j * 8), v1 = *(const f4*)(p + j * 8 + 4);
                    bf8 w = { f2bf(v0[0]), f2bf(v0[1]), f2bf(v0[2]), f2bf(v0[3]),
                              f2bf(v1[0]), f2bf(v1[1]), f2bf(v1[2]), f2bf(v1[3]) };
                    *(bf8*)(Ar + j * 8) = w;
                }
                if (q == 0) scoord[r] = coord[node];
            } else {
                bf8 z = {};
#pragma unroll
                for (int j = 0; j < 4; ++j) *(bf8*)(Ar + j * 8) = z;
                if (q == 0) scoord[r] = 0.f;
            }
        }
        __syncthreads();

        const int lane = tid & 63, wv = tid >> 6;
        const int g = lane >> 4, i16 = lane & 15, wc = wv * 64;

        f4 acc[4][4] = {};
#pragma unroll
        for (int ks = 0; ks < 4; ++ks) {
            const int kb = ks * 32 + g * 8;
            bf8 bb[4];
#pragma unroll
            for (int n = 0; n < 4; ++n)
                bb[n] = *(const bf8*)(Wpre + (wc + n * 16 + i16) * 128 + kb);
#pragma unroll
            for (int m = 0; m < 4; ++m) {
                bf8 a = *(const bf8*)(A + (m * 16 + i16) * 136 + kb);
#pragma unroll
                for (int n = 0; n < 4; ++n) acc[m][n] = MFMA(a, bb[n], acc[m][n]);
            }
        }
        __syncthreads();   // A dead -> P writable

#pragma unroll
        for (int n = 0; n < 4; ++n) {
            const int cc = wc + n * 16 + i16;
            const float wa = mW1[(288 + (cc >> 7)) * 128 + (cc & 127)];
            const float ba = (cc >> 7) ? mb1[cc - 128] : 0.f;
#pragma unroll
            for (int m = 0; m < 4; ++m)
#pragma unroll
                for (int i = 0; i < 4; ++i) {
                    const int row = m * 16 + g * 4 + i;
                    P[row * 264 + cc] = f2bf(acc[m][n][i] + scoord[row] * wa + ba);
                }
        }
        __syncthreads();

        {   // coalesced store
            const int r = tid >> 2, q = tid & 3;
            const int node = nbase + r;
            if (node < NN) {
#pragma unroll
                for (int j = 0; j < 8; ++j)
                    *(bf8*)(Ppre + (long)node * 256 + q * 64 + j * 8) =
                        *(const bf8*)(P + r * 264 + q * 64 + j * 8);
            }
        }
    } else {
        // ---- histogram of dst (218 blocks)
        const int stride = 218 * 256;
        for (int e = (b - 782) * 256 + tid; e < NE; e += stride)
            atomicAdd(&hist[ei[NE + e]], 1);
    }
}

// ---------- counting sort by dst ----------
__global__ void scan1_kernel(const int* __restrict__ hist, int* __restrict__ pos,
                             int* __restrict__ csum) {
    __shared__ int s[256];
    const int b = blockIdx.x, t = threadIdx.x;
    const int idx = b * 200 + t;
    int v = (t < 200) ? hist[idx] : 0;
    s[t] = v;
    __syncthreads();
    for (int d = 1; d < 256; d <<= 1) {
        int x = (t >= d) ? s[t - d] : 0;
        __syncthreads();
        s[t] += x;
        __syncthreads();
    }
    if (t < 200) pos[idx] = s[t] - v;
    if (t == 255) csum[b] = s[255];
}

__global__ void scan_add_kernel(int* __restrict__ pos, const int* __restrict__ csum) {
    __shared__ int sw[4];
    const int b = blockIdx.x, t = threadIdx.x;
    int v = (t < b) ? csum[t] : 0;   // b <= 249 < 256
    v += __shfl_xor(v, 1);  v += __shfl_xor(v, 2);  v += __shfl_xor(v, 4);
    v += __shfl_xor(v, 8);  v += __shfl_xor(v, 16); v += __shfl_xor(v, 32);
    if ((t & 63) == 0) sw[t >> 6] = v;
    __syncthreads();
    const int total = sw[0] + sw[1] + sw[2] + sw[3];
    if (t < 200) pos[b * 200 + t] += total;
}

// ---------- scatter+gather: materialize dst-sorted sd(int2)/efs(bf16) ----------
__global__ void scatter_kernel(const int* __restrict__ ei, const float* __restrict__ ef,
                               int* __restrict__ pos, i2* __restrict__ sd,
                               short* __restrict__ efs) {
    const int tid = threadIdx.x;
    const int lane = tid & 63;
    const int r = tid >> 2, q = tid & 3;   // 4 threads per edge
#pragma unroll
    for (int k = 0; k < 4; ++k) {
        const int e = (blockIdx.x * 4 + k) * 64 + r;
        int p = 0;
        if (q == 0) {
            const int d = ei[NE + e];
            p = atomicAdd(&pos[d], 1);
            i2 v = { ei[e], d };            // one 8B store, one line
            sd[p] = v;
        }
        p = __shfl(p, lane & 60);
        const float* pe = ef + (long)e * 32 + q * 8;
        f4 v0 = *(const f4*)pe, v1 = *(const f4*)(pe + 4);
        bf8 w = { f2bf(v0[0]), f2bf(v0[1]), f2bf(v0[2]), f2bf(v0[3]),
                  f2bf(v1[0]), f2bf(v1[1]), f2bf(v1[2]), f2bf(v1[3]) };
        *(bf8*)(efs + (long)p * 32 + q * 8) = w;
    }
}

// ---------- edge kernel: all-sequential streams + 1-level Ppre gather ----------
__global__ __launch_bounds__(256, 7)
void edge_kernel(const i2* __restrict__ sd,
                 const short* __restrict__ efs, const short* __restrict__ Ppre,
                 const short* __restrict__ W1e, const short* __restrict__ W2p,
                 const float* __restrict__ mb2, float* __restrict__ agg) {
    constexpr int LDEF = 36, LDH = 136, LDM = 132;
    __shared__ short Aef[64 * LDEF];    //  4,608 B
    __shared__ short HM[64 * LDH];      // 17,408 B — H bf16 [64][136] / Mh f32 [32][132]
    __shared__ int sdst[64], ssrc[64];  //     512 B   (total 22,528 -> 7 blocks/CU)
    short* H = HM;
    float* Mh = (float*)HM;

    const int tid = threadIdx.x;
    const int bid = blockIdx.x;
    const int ebase = ((bid & 7) * 1250 + (bid >> 3)) * 64;   // XCD-chunked swizzle

    const int lane = tid & 63, wv = tid >> 6;
    const int g = lane >> 4, i16 = lane & 15, wc = wv * 32;
    const int r = tid >> 2, q = tid & 3;

    // ---- stage: ALL sequential (sorted arrays); W-frags/bias hoisted (L2-hot)
    const int e = ebase + r;
    if (q == 0) { i2 v = sd[e]; ssrc[r] = v[0]; sdst[r] = v[1]; }
    bf8 ev = *(const bf8*)(efs + (long)e * 32 + q * 8);
    bf8 b0 = *(const bf8*)(W1e + (wc + i16) * 32 + g * 8);
    bf8 b1 = *(const bf8*)(W1e + (wc + 16 + i16) * 32 + g * 8);
    const float c0 = mb2[wc + i16], c1 = mb2[wc + 16 + i16];
    *(bf8*)(Aef + r * LDEF + q * 8) = ev;
    SYNC();

    // ---- layer-1 ef part: [64,32] @ [32,128]; partial -> H (bf16)
    {
        f4 acc[4][2] = {};
#pragma unroll
        for (int m = 0; m < 4; ++m) {
            bf8 a = *(const bf8*)(Aef + (m * 16 + i16) * LDEF + g * 8);
            acc[m][0] = MFMA(a, b0, acc[m][0]);
            acc[m][1] = MFMA(a, b1, acc[m][1]);
        }
#pragma unroll
        for (int m = 0; m < 4; ++m)
#pragma unroll
            for (int n = 0; n < 2; ++n)
#pragma unroll
                for (int i = 0; i < 4; ++i)
                    H[(m * 16 + g * 4 + i) * LDH + wc + n * 16 + i16] = f2bf(acc[m][n][i]);
    }
    SYNC();

    {   // ---- gather Ppre (the single random access, 1 dependent level) + silu
        const int s_ = ssrc[r], d_ = sdst[r];
        const short* p1 = Ppre + (long)s_ * 256 + q * 32;
        const short* p2 = Ppre + (long)d_ * 256 + 128 + q * 32;
        bf8 a1[4], a2[4];
#pragma unroll
        for (int j = 0; j < 4; ++j) a1[j] = *(const bf8*)(p1 + j * 8);
#pragma unroll
        for (int j = 0; j < 4; ++j) a2[j] = *(const bf8*)(p2 + j * 8);
        short* Hr = H + r * LDH + q * 32;
#pragma unroll
        for (int j = 0; j < 4; ++j) {
            bf8 hv = *(const bf8*)(Hr + j * 8);
            bf8 o;
#pragma unroll
            for (int t = 0; t < 8; ++t) {
                float x = bf2f(hv[t]) + bf2f(a1[j][t]) + bf2f(a2[j][t]);
                o[t] = f2bf(silu(x));
            }
            *(bf8*)(Hr + j * 8) = o;
        }
    }
    SYNC();

    // ---- layer 2: [64,128] @ [128,128]
    f4 acc2[4][2] = {};
#pragma unroll
    for (int ks = 0; ks < 4; ++ks) {
        const int kb = ks * 32 + g * 8;
        bf8 w0 = *(const bf8*)(W2p + (wc + i16) * 128 + kb);
        bf8 w1 = *(const bf8*)(W2p + (wc + 16 + i16) * 128 + kb);
#pragma unroll
        for (int m = 0; m < 4; ++m) {
            bf8 a = *(const bf8*)(H + (m * 16 + i16) * LDH + kb);
            acc2[m][0] = MFMA(a, w0, acc2[m][0]);
            acc2[m][1] = MFMA(a, w1, acc2[m][1]);
        }
    }
    SYNC();   // H dead

    // ---- half-pass A: rows 0..31 (m=0,1) -> f32 Mh, then seg-reduce
#pragma unroll
    for (int m = 0; m < 2; ++m)
#pragma unroll
        for (int n = 0; n < 2; ++n)
#pragma unroll
            for (int i = 0; i < 4; ++i)
                Mh[(m * 16 + g * 4 + i) * LDM + wc + n * 16 + i16] =
                    acc2[m][n][i] + (n ? c1 : c0);
    SYNC();
    {
        const int col = tid & 127, half = tid >> 7;
        const int base = half * 16;
        float run = 0.f;
#pragma unroll
        for (int rr = 0; rr < 16; ++rr) {
            const int row = base + rr;
            run += Mh[row * LDM + col];
            const bool last = (rr == 15) || (sdst[row + 1] != sdst[row]);
            if (last) {
                atomicAdd(agg + (long)sdst[row] * HID + col, run);
                run = 0.f;
            }
        }
    }
    SYNC();

    // ---- half-pass B: rows 32..63 (m=2,3)
#pragma unroll
    for (int m = 2; m < 4; ++m)
#pragma unroll
        for (int n = 0; n < 2; ++n)
#pragma unroll
            for (int i = 0; i < 4; ++i)
                Mh[((m - 2) * 16 + g * 4 + i) * LDM + wc + n * 16 + i16] =
                    acc2[m][n][i] + (n ? c1 : c0);
    SYNC();
    {
        const int col = tid & 127, half = tid >> 7;
        const int base = half * 16;
        float run = 0.f;
#pragma unroll
        for (int rr = 0; rr < 16; ++rr) {
            const int row = 32 + base + rr;
            run += Mh[(row - 32) * LDM + col];
            const bool last = (rr == 15) || (sdst[row + 1] != sdst[row]);
            if (last) {
                atomicAdd(agg + (long)sdst[row] * HID + col, run);
                run = 0.f;
            }
        }
    }
}

// ---------- node kernel: update MLP + residual + LayerNorm ----------
__global__ __launch_bounds__(256, 4)
void node_kernel(const float* __restrict__ nf, const float* __restrict__ agg,
                 const float* __restrict__ coord,
                 const short* __restrict__ U1p, const float* __restrict__ ub1,
                 const short* __restrict__ U2p, const float* __restrict__ ub2,
                 const float* __restrict__ gamma, const float* __restrict__ beta,
                 float* __restrict__ out) {
    constexpr int K1 = 288, LDA = 296, LDH = 136, LDX = 132;
    __shared__ short SH[64 * LDA];    // 37,888 B — A / H / X phase-disjoint
    short* A = SH;
    short* H = SH;
    float* X = (float*)SH;

    const int tid = threadIdx.x;
    const int nbase = blockIdx.x * 64;

    {   // stage [nf | agg | coord] as bf16
        const int r = tid >> 2, q = tid & 3;
        const int node = nbase + r;
        short* Ar = A + r * LDA;
        bf8 z = {};
        if (node < NN) {
            const float* pn = nf + (long)node * HID + q * 32;
            const float* pa = agg + (long)node * HID + q * 32;
#pragma unroll
            for (int j = 0; j < 4; ++j) {
                f4 v0 = *(const f4*)(pn + j * 8), v1 = *(const f4*)(pn + j * 8 + 4);
                bf8 w = { f2bf(v0[0]), f2bf(v0[1]), f2bf(v0[2]), f2bf(v0[3]),
                          f2bf(v1[0]), f2bf(v1[1]), f2bf(v1[2]), f2bf(v1[3]) };
                *(bf8*)(Ar + q * 32 + j * 8) = w;
            }
#pragma unroll
            for (int j = 0; j < 4; ++j) {
                f4 v0 = *(const f4*)(pa + j * 8), v1 = *(const f4*)(pa + j * 8 + 4);
                bf8 w = { f2bf(v0[0]), f2bf(v0[1]), f2bf(v0[2]), f2bf(v0[3]),
                          f2bf(v1[0]), f2bf(v1[1]), f2bf(v1[2]), f2bf(v1[3]) };
                *(bf8*)(Ar + 128 + q * 32 + j * 8) = w;
            }
            *(bf8*)(Ar + 256 + q * 8) = z;
            if (q == 0) Ar[256] = f2bf(coord[node]);
        } else {
#pragma unroll
            for (int j = 0; j < 4; ++j) {
                *(bf8*)(Ar + q * 32 + j * 8) = z;
                *(bf8*)(Ar + 128 + q * 32 + j * 8) = z;
            }
            *(bf8*)(Ar + 256 + q * 8) = z;
        }
    }
    SYNC();

    const int lane = tid & 63, wv = tid >> 6;
    const int g = lane >> 4, i16 = lane & 15, wc = wv * 32;

    f4 acc[4][2] = {};
#pragma unroll
    for (int ks = 0; ks < K1 / 32; ++ks) {
        const int kb = ks * 32 + g * 8;
        bf8 b0 = *(const bf8*)(U1p + (wc + i16) * K1 + kb);
        bf8 b1 = *(const bf8*)(U1p + (wc + 16 + i16) * K1 + kb);
#pragma unroll
        for (int m = 0; m < 4; ++m) {
            bf8 a = *(const bf8*)(A + (m * 16 + i16) * LDA + kb);
            acc[m][0] = MFMA(a, b0, acc[m][0]);
            acc[m][1] = MFMA(a, b1, acc[m][1]);
        }
    }
    SYNC();   // A dead

    {   // silu -> H
        const float c0 = ub1[wc + i16], c1 = ub1[wc + 16 + i16];
#pragma unroll
        for (int m = 0; m < 4; ++m)
#pragma unroll
            for (int n = 0; n < 2; ++n)
#pragma unroll
                for (int i = 0; i < 4; ++i) {
                    float x = acc[m][n][i] + (n ? c1 : c0);
                    H[(m * 16 + g * 4 + i) * LDH + wc + n * 16 + i16] = f2bf(silu(x));
                }
    }
    SYNC();

    f4 acc2[4][2] = {};
#pragma unroll
    for (int ks = 0; ks < 4; ++ks) {
        const int kb = ks * 32 + g * 8;
        bf8 b0 = *(const bf8*)(U2p + (wc + i16) * 128 + kb);
        bf8 b1 = *(const bf8*)(U2p + (wc + 16 + i16) * 128 + kb);
#pragma unroll
        for (int m = 0; m < 4; ++m) {
            bf8 a = *(const bf8*)(H + (m * 16 + i16) * LDH + kb);
            acc2[m][0] = MFMA(a, b0, acc2[m][0]);
            acc2[m][1] = MFMA(a, b1, acc2[m][1]);
        }
    }
    SYNC();   // H dead

    {   // X = nf + upd
        const float c0 = ub2[wc + i16], c1 = ub2[wc + 16 + i16];
#pragma unroll
        for (int m = 0; m < 4; ++m)
#pragma unroll
            for (int n = 0; n < 2; ++n)
#pragma unroll
                for (int i = 0; i < 4; ++i) {
                    const int row = m * 16 + g * 4 + i;
                    const int node = nbase + row;
                    const int col = wc + n * 16 + i16;
                    float v = acc2[m][n][i] + (n ? c1 : c0);
                    float base = (node < NN) ? nf[(long)node * HID + col] : 0.f;
                    X[row * LDX + col] = base + v;
                }
    }
    SYNC();

    {   // LayerNorm: 4 threads per row
        const int r = tid >> 2, q = tid & 3;
        const int node = nbase + r;
        float s = 0.f;
#pragma unroll
        for (int j = 0; j < 32; ++j) s += X[r * LDX + q * 32 + j];
        s += __shfl_xor(s, 1);
        s += __shfl_xor(s, 2);
        const float mu = s * (1.f / 128.f);
        float vv = 0.f;
#pragma unroll
        for (int j = 0; j < 32; ++j) {
            float d = X[r * LDX + q * 32 + j] - mu;
            vv += d * d;
        }
        vv += __shfl_xor(vv, 1);
        vv += __shfl_xor(vv, 2);
        const float rstd = rsqrtf(vv * (1.f / 128.f) + 1e-5f);
        if (node < NN) {
#pragma unroll
            for (int j = 0; j < 32; ++j) {
                const int c = q * 32 + j;
                out[(long)node * HID + c] = (X[r * LDX + c] - mu) * rstd * gamma[c] + beta[c];
            }
        }
    }
}

extern "C" void kernel_launch(void* const* d_in, const int* in_sizes, int n_in,
                              void* d_out, int out_size, void* d_ws, size_t ws_size,
                              hipStream_t stream) {
    const float* nf    = (const float*)d_in[0];
    const int*   ei    = (const int*)d_in[1];
    const float* ef    = (const float*)d_in[2];
    const float* coord = (const float*)d_in[3];
    const float* mW1 = (const float*)d_in[4];
    const float* mb1 = (const float*)d_in[5];
    const float* mW2 = (const float*)d_in[6];
    const float* mb2 = (const float*)d_in[7];
    const float* uW1 = (const float*)d_in[8];
    const float* ub1 = (const float*)d_in[9];
    const float* uW2 = (const float*)d_in[10];
    const float* ub2 = (const float*)d_in[11];
    const float* gamma = (const float*)d_in[12];
    const float* beta  = (const float*)d_in[13];
    float* out = (float*)d_out;

    char* ws = (char*)d_ws;
    float* agg  = (float*)ws;                    // 25,600,000
    int*   hist = (int*)(ws + 25600000);         //    200,000
    short* W1e  = (short*)(ws + 25800000);
    short* W2p  = (short*)(ws + 25808192);
    short* U1p  = (short*)(ws + 25840960);
    short* U2p  = (short*)(ws + 25914688);
    int*   pos  = (int*)(ws + 25947456);
    int*   csum = (int*)(ws + 26147456);
    i2*    sd   = (i2*)(ws + 26148480);
    short* efs  = (short*)(ws + 31268480);
    short* Wpre = efs;             // aliases efs head; dead before scatter (R8-proven)
    short* Ppre = (short*)d_out;   // scratch until node_kernel overwrites d_out

    init_kernel<<<256, 256, 0, stream>>>(mW1, mW2, uW1, uW2,
                                         Wpre, W1e, W2p, U1p, U2p, (f4*)ws);
    prep_kernel<<<1000, 256, 0, stream>>>(nf, coord, Wpre, mW1, mb1, ei, Ppre, hist);
    scan1_kernel<<<250, 256, 0, stream>>>(hist, pos, csum);
    scan_add_kernel<<<250, 256, 0, stream>>>(pos, csum);
    scatter_kernel<<<2500, 256, 0, stream>>>(ei, ef, pos, sd, efs);
    edge_kernel<<<NE / 64, 256, 0, stream>>>(sd, efs, Ppre, W1e, W2p, mb2, agg);
    node_kernel<<<782, 256, 0, stream>>>(nf, agg, coord,
                                         U1p, ub1, U2p, ub2, gamma, beta, out);
}

// Round 16
// 214.592 us; speedup vs baseline: 1.0158x; 1.0158x over previous
//
#include <hip/hip_runtime.h>
#include <hip/hip_bf16.h>

#define NN 50000
#define NE 640000
#define HID 128

// ---- workspace layout (bytes) ----  (high-water 72,228,480 — R6-proven)
// agg   f32 [NN*128]   @ 0            25,600,000   \ one memset covers both
// hist  int [50000]    @ 25,600,000      200,000   /
// W1e   bf16[128*32]   @ 25,800,000        8,192
// W2p   bf16[128*128]  @ 25,808,192       32,768
// U1p   bf16[128*288]  @ 25,840,960       73,728
// U2p   bf16[128*128]  @ 25,914,688       32,768
// pos   int [50000]    @ 25,947,456      200,000
// csum  int [256]      @ 26,147,456        1,024
// sd    int2[NE]       @ 26,148,480    5,120,000   (dst-sorted {src,dst} pairs)
// efs   bf16[NE*32]    @ 31,268,480   40,960,000   (dst-sorted, bf16)
// Ppre bf16[NN*256] lives in d_out (dead until node_kernel).

typedef __attribute__((ext_vector_type(8))) short bf8;  // 8 bf16 = 16B
typedef __attribute__((ext_vector_type(4))) float f4;
typedef __attribute__((ext_vector_type(2))) int i2;

#define MFMA(a, b, c) __builtin_amdgcn_mfma_f32_16x16x32_bf16(a, b, c, 0, 0, 0)

// Raw barrier: LDS visibility only (lgkmcnt), does NOT drain vmcnt.
#define SYNC() do { asm volatile("s_waitcnt lgkmcnt(0)" ::: "memory"); \
                    __builtin_amdgcn_s_barrier(); } while (0)

// f32 -> bf16 (RNE) via the official HW convert path. NO hand-written
// v_cvt_pk asm — convicted of NaN corruption in R7/R10.
__device__ __forceinline__ short f2bf(float f) {
    __hip_bfloat16 h = __float2bfloat16(f);
    union { __hip_bfloat16 h; short s; } v; v.h = h;
    return v.s;
}
__device__ __forceinline__ float bf2f(short s) {
    union { unsigned u; float f; } v; v.u = ((unsigned)(unsigned short)s) << 16;
    return v.f;
}
__device__ __forceinline__ float silu(float x) {
    return x * __builtin_amdgcn_rcpf(1.f + __expf(-x));
}

// ---------- prep: node_pre (blocks 0..781) | pack (782..845) | hist (846..999) ----------
__global__ __launch_bounds__(256, 3)
void prep_kernel(const float* __restrict__ nf, const float* __restrict__ coord,
                 const float* __restrict__ mW1, const float* __restrict__ mb1,
                 const float* __restrict__ mW2,
                 const float* __restrict__ uW1, const float* __restrict__ uW2,
                 const int* __restrict__ ei,
                 short* __restrict__ W1e, short* __restrict__ W2p,
                 short* __restrict__ U1p, short* __restrict__ U2p,
                 short* __restrict__ Ppre, int* __restrict__ hist) {
    const int b = blockIdx.x, tid = threadIdx.x;
    if (b < 782) {
        // Ppre[n] = [nf@W1src + c*w288 | nf@W1dst + c*w289 + mb1]
        __shared__ short SH[64 * 264];   // A [64][136] then P [64][264] (phase-disjoint)
        __shared__ float scoord[64];
        short* A = SH;
        short* P = SH;
        const int nbase = b * 64;

        {   // stage nf -> bf16 A
            const int r = tid >> 2, q = tid & 3;
            const int node = nbase + r;
            short* Ar = A + r * 136 + q * 32;
            if (node < NN) {
                const float* p = nf + (long)node * HID + q * 32;
#pragma unroll
                for (int j = 0; j < 4; ++j) {
                    f4 v0 = *(const f4*)(p + j * 8), v1 = *(const f4*)(p + j * 8 + 4);
                    bf8 w = { f2bf(v0[0]), f2bf(v0[1]), f2bf(v0[2]), f2bf(v0[3]),
                              f2bf(v1[0]), f2bf(v1[1]), f2bf(v1[2]), f2bf(v1[3]) };
                    *(bf8*)(Ar + j * 8) = w;
                }
                if (q == 0) scoord[r] = coord[node];
            } else {
                bf8 z = {};
#pragma unroll
                for (int j = 0; j < 4; ++j) *(bf8*)(Ar + j * 8) = z;
                if (q == 0) scoord[r] = 0.f;
            }
        }
        __syncthreads();

        const int lane = tid & 63, wv = tid >> 6;
        const int g = lane >> 4, i16 = lane & 15, wc = wv * 64;

        f4 acc[4][4] = {};
#pragma unroll
        for (int ks = 0; ks < 4; ++ks) {
            const int kb = ks * 32 + g * 8;
            bf8 bfr[4];
#pragma unroll
            for (int n = 0; n < 4; ++n) {
                const int cc = wc + n * 16 + i16;
                const float* wp = mW1 + ((cc >> 7) ? (128 * 128 + (cc - 128)) : cc);
#pragma unroll
                for (int j = 0; j < 8; ++j)
                    bfr[n][j] = f2bf(wp[(kb + j) * 128]);
            }
#pragma unroll
            for (int m = 0; m < 4; ++m) {
                bf8 a = *(const bf8*)(A + (m * 16 + i16) * 136 + kb);
#pragma unroll
                for (int n = 0; n < 4; ++n) acc[m][n] = MFMA(a, bfr[n], acc[m][n]);
            }
        }
        __syncthreads();   // A dead -> P writable

#pragma unroll
        for (int n = 0; n < 4; ++n) {
            const int cc = wc + n * 16 + i16;
            const float wa = mW1[(288 + (cc >> 7)) * 128 + (cc & 127)];
            const float ba = (cc >> 7) ? mb1[cc - 128] : 0.f;
#pragma unroll
            for (int m = 0; m < 4; ++m)
#pragma unroll
                for (int i = 0; i < 4; ++i) {
                    const int row = m * 16 + g * 4 + i;
                    P[row * 264 + cc] = f2bf(acc[m][n][i] + scoord[row] * wa + ba);
                }
        }
        __syncthreads();

        {   // coalesced store
            const int r = tid >> 2, q = tid & 3;
            const int node = nbase + r;
            if (node < NN) {
#pragma unroll
                for (int j = 0; j < 8; ++j)
                    *(bf8*)(Ppre + (long)node * 256 + q * 64 + j * 8) =
                        *(const bf8*)(P + r * 264 + q * 64 + j * 8);
            }
        }
    } else if (b < 846) {
        // ---- pack the B-operand weights used by edge/node kernels
        const int stride = 64 * 256;
        const int idx = (b - 782) * 256 + tid;
        for (int t = idx; t < 128 * 32; t += stride) {
            int c = t / 32, k = t % 32;
            W1e[t] = f2bf(mW1[(256 + k) * 128 + c]);
        }
        for (int t = idx; t < 128 * 128; t += stride)
            W2p[t] = f2bf(mW2[(t % 128) * 128 + (t / 128)]);
        for (int t = idx; t < 128 * 288; t += stride) {
            int n = t / 288, k = t % 288;
            U1p[t] = (k < 257) ? f2bf(uW1[k * 128 + n]) : (short)0;
        }
        for (int t = idx; t < 128 * 128; t += stride)
            U2p[t] = f2bf(uW2[(t % 128) * 128 + (t / 128)]);
    } else {
        // ---- histogram of dst
        const int stride = 154 * 256;
        for (int e = (b - 846) * 256 + tid; e < NE; e += stride)
            atomicAdd(&hist[ei[NE + e]], 1);
    }
}

// ---------- counting sort by dst ----------
__global__ void scan1_kernel(const int* __restrict__ hist, int* __restrict__ pos,
                             int* __restrict__ csum) {
    __shared__ int s[256];
    const int b = blockIdx.x, t = threadIdx.x;
    const int idx = b * 200 + t;
    int v = (t < 200) ? hist[idx] : 0;
    s[t] = v;
    __syncthreads();
    for (int d = 1; d < 256; d <<= 1) {
        int x = (t >= d) ? s[t - d] : 0;
        __syncthreads();
        s[t] += x;
        __syncthreads();
    }
    if (t < 200) pos[idx] = s[t] - v;
    if (t == 255) csum[b] = s[255];
}

__global__ void scan_add_kernel(int* __restrict__ pos, const int* __restrict__ csum) {
    __shared__ int sw[4];
    const int b = blockIdx.x, t = threadIdx.x;
    int v = (t < b) ? csum[t] : 0;   // b <= 249 < 256
    v += __shfl_xor(v, 1);  v += __shfl_xor(v, 2);  v += __shfl_xor(v, 4);
    v += __shfl_xor(v, 8);  v += __shfl_xor(v, 16); v += __shfl_xor(v, 32);
    if ((t & 63) == 0) sw[t >> 6] = v;
    __syncthreads();
    const int total = sw[0] + sw[1] + sw[2] + sw[3];
    if (t < 200) pos[b * 200 + t] += total;
}

// ---------- scatter+gather: materialize dst-sorted sd(int2)/efs(bf16) ----------
__global__ void scatter_kernel(const int* __restrict__ ei, const float* __restrict__ ef,
                               int* __restrict__ pos, i2* __restrict__ sd,
                               short* __restrict__ efs) {
    const int tid = threadIdx.x;
    const int lane = tid & 63;
    const int r = tid >> 2, q = tid & 3;   // 4 threads per edge
#pragma unroll
    for (int k = 0; k < 4; ++k) {
        const int e = (blockIdx.x * 4 + k) * 64 + r;
        int p = 0;
        if (q == 0) {
            const int d = ei[NE + e];
            p = atomicAdd(&pos[d], 1);
            i2 v = { ei[e], d };            // one 8B store, one line (vs 2x4B, 2 lines)
            sd[p] = v;
        }
        p = __shfl(p, lane & 60);
        const float* pe = ef + (long)e * 32 + q * 8;
        f4 v0 = *(const f4*)pe, v1 = *(const f4*)(pe + 4);
        bf8 w = { f2bf(v0[0]), f2bf(v0[1]), f2bf(v0[2]), f2bf(v0[3]),
                  f2bf(v1[0]), f2bf(v1[1]), f2bf(v1[2]), f2bf(v1[3]) };
        *(bf8*)(efs + (long)p * 32 + q * 8) = w;
    }
}

// ---------- edge kernel: all-sequential streams + 1-level Ppre gather ----------
__global__ __launch_bounds__(256, 7)
void edge_kernel(const i2* __restrict__ sd,
                 const short* __restrict__ efs, const short* __restrict__ Ppre,
                 const short* __restrict__ W1e, const short* __restrict__ W2p,
                 const float* __restrict__ mb2, float* __restrict__ agg) {
    constexpr int LDEF = 36, LDH = 136, LDM = 132;
    __shared__ short Aef[64 * LDEF];    //  4,608 B
    __shared__ short HM[64 * LDH];      // 17,408 B — H bf16 [64][136] / Mh f32 [32][132]
    __shared__ int sdst[64], ssrc[64];  //     512 B   (total 22,528 -> 7 blocks/CU)
    short* H = HM;
    float* Mh = (float*)HM;

    const int tid = threadIdx.x;
    const int bid = blockIdx.x;
    const int ebase = ((bid & 7) * 1250 + (bid >> 3)) * 64;   // XCD-chunked swizzle

    const int lane = tid & 63, wv = tid >> 6;
    const int g = lane >> 4, i16 = lane & 15, wc = wv * 32;
    const int r = tid >> 2, q = tid & 3;

    // ---- stage: ALL sequential (sorted arrays); W-frags/bias hoisted (L2-hot)
    const int e = ebase + r;
    if (q == 0) { i2 v = sd[e]; ssrc[r] = v[0]; sdst[r] = v[1]; }
    bf8 ev = *(const bf8*)(efs + (long)e * 32 + q * 8);
    bf8 b0 = *(const bf8*)(W1e + (wc + i16) * 32 + g * 8);
    bf8 b1 = *(const bf8*)(W1e + (wc + 16 + i16) * 32 + g * 8);
    const float c0 = mb2[wc + i16], c1 = mb2[wc + 16 + i16];
    *(bf8*)(Aef + r * LDEF + q * 8) = ev;
    SYNC();

    // ---- layer-1 ef part: [64,32] @ [32,128]; partial -> H (bf16)
    {
        f4 acc[4][2] = {};
#pragma unroll
        for (int m = 0; m < 4; ++m) {
            bf8 a = *(const bf8*)(Aef + (m * 16 + i16) * LDEF + g * 8);
            acc[m][0] = MFMA(a, b0, acc[m][0]);
            acc[m][1] = MFMA(a, b1, acc[m][1]);
        }
#pragma unroll
        for (int m = 0; m < 4; ++m)
#pragma unroll
            for (int n = 0; n < 2; ++n)
#pragma unroll
                for (int i = 0; i < 4; ++i)
                    H[(m * 16 + g * 4 + i) * LDH + wc + n * 16 + i16] = f2bf(acc[m][n][i]);
    }
    SYNC();

    {   // ---- gather Ppre (the single random access, 1 dependent level) + silu
        const int s_ = ssrc[r], d_ = sdst[r];
        const short* p1 = Ppre + (long)s_ * 256 + q * 32;
        const short* p2 = Ppre + (long)d_ * 256 + 128 + q * 32;
        bf8 a1[4], a2[4];
#pragma unroll
        for (int j = 0; j < 4; ++j) a1[j] = *(const bf8*)(p1 + j * 8);
#pragma unroll
        for (int j = 0; j < 4; ++j) a2[j] = *(const bf8*)(p2 + j * 8);
        short* Hr = H + r * LDH + q * 32;
#pragma unroll
        for (int j = 0; j < 4; ++j) {
            bf8 hv = *(const bf8*)(Hr + j * 8);
            bf8 o;
#pragma unroll
            for (int t = 0; t < 8; ++t) {
                float x = bf2f(hv[t]) + bf2f(a1[j][t]) + bf2f(a2[j][t]);
                o[t] = f2bf(silu(x));
            }
            *(bf8*)(Hr + j * 8) = o;
        }
    }
    SYNC();

    // ---- layer 2: [64,128] @ [128,128]
    f4 acc2[4][2] = {};
#pragma unroll
    for (int ks = 0; ks < 4; ++ks) {
        const int kb = ks * 32 + g * 8;
        bf8 w0 = *(const bf8*)(W2p + (wc + i16) * 128 + kb);
        bf8 w1 = *(const bf8*)(W2p + (wc + 16 + i16) * 128 + kb);
#pragma unroll
        for (int m = 0; m < 4; ++m) {
            bf8 a = *(const bf8*)(H + (m * 16 + i16) * LDH + kb);
            acc2[m][0] = MFMA(a, w0, acc2[m][0]);
            acc2[m][1] = MFMA(a, w1, acc2[m][1]);
        }
    }
    SYNC();   // H dead

    // ---- half-pass A: rows 0..31 (m=0,1) -> f32 Mh, then seg-reduce
#pragma unroll
    for (int m = 0; m < 2; ++m)
#pragma unroll
        for (int n = 0; n < 2; ++n)
#pragma unroll
            for (int i = 0; i < 4; ++i)
                Mh[(m * 16 + g * 4 + i) * LDM + wc + n * 16 + i16] =
                    acc2[m][n][i] + (n ? c1 : c0);
    SYNC();
    {
        const int col = tid & 127, half = tid >> 7;
        const int base = half * 16;
        float run = 0.f;
#pragma unroll
        for (int rr = 0; rr < 16; ++rr) {
            const int row = base + rr;
            run += Mh[row * LDM + col];
            const bool last = (rr == 15) || (sdst[row + 1] != sdst[row]);
            if (last) {
                atomicAdd(agg + (long)sdst[row] * HID + col, run);
                run = 0.f;
            }
        }
    }
    SYNC();

    // ---- half-pass B: rows 32..63 (m=2,3)
#pragma unroll
    for (int m = 2; m < 4; ++m)
#pragma unroll
        for (int n = 0; n < 2; ++n)
#pragma unroll
            for (int i = 0; i < 4; ++i)
                Mh[((m - 2) * 16 + g * 4 + i) * LDM + wc + n * 16 + i16] =
                    acc2[m][n][i] + (n ? c1 : c0);
    SYNC();
    {
        const int col = tid & 127, half = tid >> 7;
        const int base = half * 16;
        float run = 0.f;
#pragma unroll
        for (int rr = 0; rr < 16; ++rr) {
            const int row = 32 + base + rr;
            run += Mh[(row - 32) * LDM + col];
            const bool last = (rr == 15) || (sdst[row + 1] != sdst[row]);
            if (last) {
                atomicAdd(agg + (long)sdst[row] * HID + col, run);
                run = 0.f;
            }
        }
    }
}

// ---------- node kernel: update MLP + residual + LayerNorm ----------
__global__ __launch_bounds__(256, 4)
void node_kernel(const float* __restrict__ nf, const float* __restrict__ agg,
                 const float* __restrict__ coord,
                 const short* __restrict__ U1p, const float* __restrict__ ub1,
                 const short* __restrict__ U2p, const float* __restrict__ ub2,
                 const float* __restrict__ gamma, const float* __restrict__ beta,
                 float* __restrict__ out) {
    constexpr int K1 = 288, LDA = 296, LDH = 136, LDX = 132;
    __shared__ short SH[64 * LDA];    // 37,888 B — A / H / X phase-disjoint
    short* A = SH;
    short* H = SH;
    float* X = (float*)SH;

    const int tid = threadIdx.x;
    const int nbase = blockIdx.x * 64;

    {   // stage [nf | agg | coord] as bf16
        const int r = tid >> 2, q = tid & 3;
        const int node = nbase + r;
        short* Ar = A + r * LDA;
        bf8 z = {};
        if (node < NN) {
            const float* pn = nf + (long)node * HID + q * 32;
            const float* pa = agg + (long)node * HID + q * 32;
#pragma unroll
            for (int j = 0; j < 4; ++j) {
                f4 v0 = *(const f4*)(pn + j * 8), v1 = *(const f4*)(pn + j * 8 + 4);
                bf8 w = { f2bf(v0[0]), f2bf(v0[1]), f2bf(v0[2]), f2bf(v0[3]),
                          f2bf(v1[0]), f2bf(v1[1]), f2bf(v1[2]), f2bf(v1[3]) };
                *(bf8*)(Ar + q * 32 + j * 8) = w;
            }
#pragma unroll
            for (int j = 0; j < 4; ++j) {
                f4 v0 = *(const f4*)(pa + j * 8), v1 = *(const f4*)(pa + j * 8 + 4);
                bf8 w = { f2bf(v0[0]), f2bf(v0[1]), f2bf(v0[2]), f2bf(v0[3]),
                          f2bf(v1[0]), f2bf(v1[1]), f2bf(v1[2]), f2bf(v1[3]) };
                *(bf8*)(Ar + 128 + q * 32 + j * 8) = w;
            }
            *(bf8*)(Ar + 256 + q * 8) = z;
            if (q == 0) Ar[256] = f2bf(coord[node]);
        } else {
#pragma unroll
            for (int j = 0; j < 4; ++j) {
                *(bf8*)(Ar + q * 32 + j * 8) = z;
                *(bf8*)(Ar + 128 + q * 32 + j * 8) = z;
            }
            *(bf8*)(Ar + 256 + q * 8) = z;
        }
    }
    SYNC();

    const int lane = tid & 63, wv = tid >> 6;
    const int g = lane >> 4, i16 = lane & 15, wc = wv * 32;

    f4 acc[4][2] = {};
#pragma unroll
    for (int ks = 0; ks < K1 / 32; ++ks) {
        const int kb = ks * 32 + g * 8;
        bf8 b0 = *(const bf8*)(U1p + (wc + i16) * K1 + kb);
        bf8 b1 = *(const bf8*)(U1p + (wc + 16 + i16) * K1 + kb);
#pragma unroll
        for (int m = 0; m < 4; ++m) {
            bf8 a = *(const bf8*)(A + (m * 16 + i16) * LDA + kb);
            acc[m][0] = MFMA(a, b0, acc[m][0]);
            acc[m][1] = MFMA(a, b1, acc[m][1]);
        }
    }
    SYNC();   // A dead

    {   // silu -> H
        const float c0 = ub1[wc + i16], c1 = ub1[wc + 16 + i16];
#pragma unroll
        for (int m = 0; m < 4; ++m)
#pragma unroll
            for (int n = 0; n < 2; ++n)
#pragma unroll
                for (int i = 0; i < 4; ++i) {
                    float x = acc[m][n][i] + (n ? c1 : c0);
                    H[(m * 16 + g * 4 + i) * LDH + wc + n * 16 + i16] = f2bf(silu(x));
                }
    }
    SYNC();

    f4 acc2[4][2] = {};
#pragma unroll
    for (int ks = 0; ks < 4; ++ks) {
        const int kb = ks * 32 + g * 8;
        bf8 b0 = *(const bf8*)(U2p + (wc + i16) * 128 + kb);
        bf8 b1 = *(const bf8*)(U2p + (wc + 16 + i16) * 128 + kb);
#pragma unroll
        for (int m = 0; m < 4; ++m) {
            bf8 a = *(const bf8*)(H + (m * 16 + i16) * LDH + kb);
            acc2[m][0] = MFMA(a, b0, acc2[m][0]);
            acc2[m][1] = MFMA(a, b1, acc2[m][1]);
        }
    }
    SYNC();   // H dead

    {   // X = nf + upd
        const float c0 = ub2[wc + i16], c1 = ub2[wc + 16 + i16];
#pragma unroll
        for (int m = 0; m < 4; ++m)
#pragma unroll
            for (int n = 0; n < 2; ++n)
#pragma unroll
                for (int i = 0; i < 4; ++i) {
                    const int row = m * 16 + g * 4 + i;
                    const int node = nbase + row;
                    const int col = wc + n * 16 + i16;
                    float v = acc2[m][n][i] + (n ? c1 : c0);
                    float base = (node < NN) ? nf[(long)node * HID + col] : 0.f;
                    X[row * LDX + col] = base + v;
                }
    }
    SYNC();

    {   // LayerNorm: 4 threads per row
        const int r = tid >> 2, q = tid & 3;
        const int node = nbase + r;
        float s = 0.f;
#pragma unroll
        for (int j = 0; j < 32; ++j) s += X[r * LDX + q * 32 + j];
        s += __shfl_xor(s, 1);
        s += __shfl_xor(s, 2);
        const float mu = s * (1.f / 128.f);
        float vv = 0.f;
#pragma unroll
        for (int j = 0; j < 32; ++j) {
            float d = X[r * LDX + q * 32 + j] - mu;
            vv += d * d;
        }
        vv += __shfl_xor(vv, 1);
        vv += __shfl_xor(vv, 2);
        const float rstd = rsqrtf(vv * (1.f / 128.f) + 1e-5f);
        if (node < NN) {
#pragma unroll
            for (int j = 0; j < 32; ++j) {
                const int c = q * 32 + j;
                out[(long)node * HID + c] = (X[r * LDX + c] - mu) * rstd * gamma[c] + beta[c];
            }
        }
    }
}

extern "C" void kernel_launch(void* const* d_in, const int* in_sizes, int n_in,
                              void* d_out, int out_size, void* d_ws, size_t ws_size,
                              hipStream_t stream) {
    const float* nf    = (const float*)d_in[0];
    const int*   ei    = (const int*)d_in[1];
    const float* ef    = (const float*)d_in[2];
    const float* coord = (const float*)d_in[3];
    const float* mW1 = (const float*)d_in[4];
    const float* mb1 = (const float*)d_in[5];
    const float* mW2 = (const float*)d_in[6];
    const float* mb2 = (const float*)d_in[7];
    const float* uW1 = (const float*)d_in[8];
    const float* ub1 = (const float*)d_in[9];
    const float* uW2 = (const float*)d_in[10];
    const float* ub2 = (const float*)d_in[11];
    const float* gamma = (const float*)d_in[12];
    const float* beta  = (const float*)d_in[13];
    float* out = (float*)d_out;

    char* ws = (char*)d_ws;
    float* agg  = (float*)ws;                    // 25,600,000
    int*   hist = (int*)(ws + 25600000);         //    200,000  (memset with agg)
    short* W1e  = (short*)(ws + 25800000);
    short* W2p  = (short*)(ws + 25808192);
    short* U1p  = (short*)(ws + 25840960);
    short* U2p  = (short*)(ws + 25914688);
    int*   pos  = (int*)(ws + 25947456);
    int*   csum = (int*)(ws + 26147456);
    i2*    sd   = (i2*)(ws + 26148480);
    short* efs  = (short*)(ws + 31268480);
    short* Ppre = (short*)d_out;   // scratch until node_kernel overwrites d_out

    hipMemsetAsync(ws, 0, 25800000, stream);     // agg + hist in one shot
    prep_kernel<<<1000, 256, 0, stream>>>(nf, coord, mW1, mb1, mW2, uW1, uW2, ei,
                                          W1e, W2p, U1p, U2p, Ppre, hist);
    scan1_kernel<<<250, 256, 0, stream>>>(hist, pos, csum);
    scan_add_kernel<<<250, 256, 0, stream>>>(pos, csum);
    scatter_kernel<<<2500, 256, 0, stream>>>(ei, ef, pos, sd, efs);
    edge_kernel<<<NE / 64, 256, 0, stream>>>(sd, efs, Ppre, W1e, W2p, mb2, agg);
    node_kernel<<<782, 256, 0, stream>>>(nf, agg, coord,
                                         U1p, ub1, U2p, ub2, gamma, beta, out);
}